// Round 7
// baseline (660.654 us; speedup 1.0000x reference)
//
#include <hip/hip_runtime.h>
#include <hip/hip_cooperative_groups.h>
#include <hip/hip_bf16.h>

namespace cg = cooperative_groups;

typedef __hip_bfloat16 bf16;
typedef __attribute__((ext_vector_type(8))) short bf16x8;
typedef __attribute__((ext_vector_type(4))) float f32x4;

#define NNODE 512
#define NEDGE 16384
#define INLEN 17929
#define K1    1056

// ---- workspace layout (offsets in floats) ----
#define WS_EA      0         // 16384
#define WS_CSRC    16384     // 16384 (int)
#define WS_CEA     32768     // 16384
#define WS_DEG     49152     // 512 (int)
#define WS_STARTS  49664     // 512 (int)
#define WS_LATTR   50176     // 512
#define WS_MM      50688     // 2
#define WS_MMP     50690     // 128
#define WS_STOPV   50818     // 512
#define WS_AE      51330     // 16
#define WS_PS      51346     // 4096
#define WS_H       55552     // 512*256
#define WS_G2WT    186624    // 256*256
#define WS_H2      317696    // 512*256
#define WS_ASRC    448768    // 512*8
#define WS_ADST    452864    // 512*8
#define WS_UV      456960    // 512*64
#define WS_K       489728    // 512
#define WS_APACK   490240    // bf16 512*1056 -> 270336 floats
#define WS_BPACK   760576    // bf16 512*1056 -> 270336 floats
#define WS_OUT1    1030912   // bf16 512*512  -> 131072 floats
#define WS_WC2B    1161984   // bf16 512*512  -> 131072 floats
#define WS_WESF    1293056   // 64*256
#define WS_ASRC2   1309440   // 512*8
#define WS_ADST2   1313536   // 512*8
#define WS_CURSOR  1317632   // 512 (int)
#define WS_DEGP    1318144   // 64*512 (int)
#define WS_LSUMP   1350912   // 64*512
// end = 1383680 floats ≈ 5.5 MB

struct SharedU {
  union {
    struct { short Als[2048]; short Bls[2048]; } ge;          // 8 KB (max)
    struct { float T[32][33]; } tr;
    struct { float AE[8],m[8],den[8],alpha[8],L[256],xrow[256],uvrow[64]; } ag;
    struct { int a[512]; int b[512]; } sc;
    struct { float smn[256], smx[256]; } mm;
    struct { float besf[32]; float red[256]; } sk;
    struct { int hd[512]; float hf[512]; } hi;
  };
};

// ---- MFMA 64x64 tile (device fn) ------------------------------------------
template<bool RELU, bool BF16OUT>
__device__ __forceinline__
void gemm_tile(const bf16* __restrict__ A, const bf16* __restrict__ B,
               const float* __restrict__ bias, float* __restrict__ Cf,
               bf16* __restrict__ Cb, int N, int K, int bm, int bn,
               int tid, short* Als, short* Bls){
  const int wave = tid>>6, lane = tid&63;
  const int wm = wave>>1, wn = wave&1;
  const int r = lane&15, q = lane>>4;
  f32x4 acc[2][2] = {};
  const int lrow = tid>>2, lq = tid&3;
  const bf16* Ag = A + (size_t)(bm+lrow)*K + lq*8;
  const bf16* Bg = B + (size_t)(bn+lrow)*K + lq*8;
  const int sidx = (lq*64+lrow)*8;
  for (int k0=0; k0<K; k0+=32){
    float4 av = *(const float4*)(Ag + k0);
    float4 bv = *(const float4*)(Bg + k0);
    *(float4*)(&Als[sidx]) = av;
    *(float4*)(&Bls[sidx]) = bv;
    __syncthreads();
    #pragma unroll
    for (int i=0;i<2;i++){
      bf16x8 af = *(const bf16x8*)(&Als[(q*64 + wm*32 + i*16 + r)*8]);
      #pragma unroll
      for (int j=0;j<2;j++){
        bf16x8 bfr = *(const bf16x8*)(&Bls[(q*64 + wn*32 + j*16 + r)*8]);
        acc[i][j] = __builtin_amdgcn_mfma_f32_16x16x32_bf16(af, bfr, acc[i][j], 0,0,0);
      }
    }
    __syncthreads();
  }
  #pragma unroll
  for (int i=0;i<2;i++){
    int row = bm + wm*32 + i*16 + q*4;
    #pragma unroll
    for (int j=0;j<2;j++){
      int col = bn + wn*32 + j*16 + r;
      float bi = bias ? bias[col] : 0.f;
      #pragma unroll
      for (int g=0; g<4; g++){
        float v = acc[i][j][g] + bi;
        if (RELU) v = fmaxf(v, 0.f);
        if (BF16OUT) Cb[(size_t)(row+g)*N + col] = __float2bfloat16(v);
        else         Cf[(size_t)(row+g)*N + col] = v;
      }
    }
  }
}

// ---- GAT aggregate phase (device fn) ---------------------------------------
template<int MODE>
__device__ void agg_phase(const float* __restrict__ hbuf, const float* __restrict__ asrc,
    const float* __restrict__ adst, const int* __restrict__ csrc, const float* __restrict__ cea,
    const int* __restrict__ starts, const int* __restrict__ deg, const float* __restrict__ lattr,
    const float* __restrict__ AEp, const float* __restrict__ bvec,
    const float* __restrict__ dist, const float* __restrict__ markov,
    float* ws, int t, int tid, SharedU& sh){
  int hd = tid>>5;
  if (tid < 8) sh.ag.AE[tid] = AEp[tid];
  __syncthreads();
  int d = deg[t], s0 = starts[t];
  if (tid < 8){
    float aself = asrc[t*8+tid] + adst[t*8+tid] + lattr[t]*sh.ag.AE[tid];
    aself = aself>=0.f ? aself : 0.2f*aself;
    sh.ag.m[tid] = aself; sh.ag.den[tid] = 1.0f;
  }
  __syncthreads();
  float acc = hbuf[t*256+tid];
  int el = tid>>3, h2i = tid&7;
  float adt2 = adst[t*8+h2i], ae2 = sh.ag.AE[h2i];
  for (int e0=0; e0<d; e0+=32){
    int ce = d-e0 < 32 ? d-e0 : 32;
    float lg = -3.4e38f;
    if (el < ce){
      int src = csrc[s0+e0+el];
      float a = asrc[src*8+h2i] + adt2 + cea[s0+e0+el]*ae2;
      lg = a>=0.f ? a : 0.2f*a;
    }
    sh.ag.L[el*8+h2i] = lg;
    __syncthreads();
    if (tid < 8){
      float mm = sh.ag.m[tid];
      for (int e=0;e<ce;e++) mm = fmaxf(mm, sh.ag.L[e*8+tid]);
      float al = __expf(sh.ag.m[tid]-mm);
      float dd = sh.ag.den[tid]*al;
      for (int e=0;e<ce;e++) dd += __expf(sh.ag.L[e*8+tid]-mm);
      sh.ag.m[tid]=mm; sh.ag.den[tid]=dd; sh.ag.alpha[tid]=al;
    }
    __syncthreads();
    if (el < ce) sh.ag.L[el*8+h2i] = __expf(lg - sh.ag.m[h2i]);
    __syncthreads();
    acc *= sh.ag.alpha[hd];
    for (int e=0;e<ce;e++){
      int sre = csrc[s0+e0+e];
      acc += sh.ag.L[e*8+hd] * hbuf[sre*256+tid];
    }
    __syncthreads();
  }
  float v = fmaxf(acc/sh.ag.den[hd] + bvec[tid], 0.f);
  sh.ag.xrow[tid] = v;
  __syncthreads();
  if (MODE == 1){
    const float* g2wt = ws + WS_G2WT;
    float hr = 0.f;
    for (int c=0;c<256;c++) hr += sh.ag.xrow[c] * g2wt[c*256 + tid];
    ws[WS_H2 + t*256 + tid] = hr;
    if (tid < 64){
      int j = tid>>2, q = tid&3;
      const float* pr = ws + WS_PS + j*256 + q*64;
      const float* xr = sh.ag.xrow + q*64;
      float p = 0.f;
      for (int c=0;c<64;c++) p += xr[c]*pr[c];
      p += __shfl_down(p,2,4);
      p += __shfl_down(p,1,4);
      if (q==0){
        if (j<8) ws[WS_ASRC2 + t*8+j] = p;
        else     ws[WS_ADST2 + t*8+(j-8)] = p;
      }
    }
  } else {
    int k = tid>>2, q = tid&3;
    const float* wr = ws + WS_WESF + k*256 + q*64;
    const float* xr = sh.ag.xrow + q*64;
    float p = 0.f;
    for (int c=0;c<64;c++) p += xr[c]*wr[c];
    p += __shfl_down(p,2,4);
    p += __shfl_down(p,1,4);
    if (q==0){ ws[WS_UV + t*64+k] = p; sh.ag.uvrow[k] = p; }
    __syncthreads();
    float mn = ws[WS_MM], mx = ws[WS_MM+1];
    float inv = 1.0f/(mx-mn);
    bf16* ap = (bf16*)(ws+WS_APACK);
    for (int j=tid; j<K1; j+=256){
      float v2;
      if (j<32)       v2 = sh.ag.uvrow[j];
      else if (j<544) v2 = (dist[t*512 + j-32] - mn) * inv;
      else            v2 = markov[t*512 + j-544];
      ap[(size_t)t*K1 + j] = __float2bfloat16(v2);
    }
  }
}

// ================= the cooperative mega-kernel ==============================
__global__ __launch_bounds__(256, 2)
void mega(const float* __restrict__ dist, const float* __restrict__ markov,
          const float* __restrict__ demand, const float* __restrict__ Wweek,
          const float* __restrict__ Wcap, const float* __restrict__ Wveh,
          const float* __restrict__ g1W, const float* __restrict__ g1as,
          const float* __restrict__ g1ad, const float* __restrict__ g1We,
          const float* __restrict__ g1ae, const float* __restrict__ g1b,
          const float* __restrict__ g2W, const float* __restrict__ g2as,
          const float* __restrict__ g2ad, const float* __restrict__ g2We,
          const float* __restrict__ g2ae, const float* __restrict__ g2b,
          const float* __restrict__ Wes, const float* __restrict__ bes,
          const float* __restrict__ Wc1, const float* __restrict__ bc1,
          const float* __restrict__ Wc2, const float* __restrict__ bc2,
          const int* __restrict__ stops, const int* __restrict__ eidx,
          const int* __restrict__ wd, const int* __restrict__ vh,
          const int* __restrict__ cp, float* __restrict__ out, float* ws){
  __shared__ SharedU sh;
  cg::grid_group grid = cg::this_grid();
  const int b = blockIdx.x, tid = threadIdx.x;

  // ---------- Phase A: input-only prep ----------
  {
    // row work: layer-1 h + logits (all 512 blocks)
    int hd = tid>>5, c = tid&31;
    float hv = demand[b] * g1W[tid];
    ws[WS_H + b*256 + tid] = hv;
    float ps = hv * g1as[tid];
    float pd = hv * g1ad[tid];
    for (int off=16; off; off>>=1){ ps += __shfl_down(ps,off,32); pd += __shfl_down(pd,off,32); }
    if (c==0){ ws[WS_ASRC + b*8+hd]=ps; ws[WS_ADST + b*8+hd]=pd; }
  }
  if (b < 64){
    // dist minmax partial
    float mn = 3.4e38f, mx = -3.4e38f;
    for (int k=0;k<16;k++){
      float v = dist[b*4096 + k*256 + tid];
      mn = fminf(mn,v); mx = fmaxf(mx,v);
    }
    sh.mm.smn[tid]=mn; sh.mm.smx[tid]=mx; __syncthreads();
    for (int off=128; off; off>>=1){
      if (tid<off){ sh.mm.smn[tid]=fminf(sh.mm.smn[tid],sh.mm.smn[tid+off]);
                    sh.mm.smx[tid]=fmaxf(sh.mm.smx[tid],sh.mm.smx[tid+off]); }
      __syncthreads();
    }
    if (tid==0){ ws[WS_MMP+b]=sh.mm.smn[0]; ws[WS_MMP+64+b]=sh.mm.smx[0]; }
  } else if (b < 128){
    // ea gather + per-block partial histogram (no atomics on global)
    int k = b-64;
    sh.hi.hd[tid]=0; sh.hi.hd[256+tid]=0; sh.hi.hf[tid]=0.f; sh.hi.hf[256+tid]=0.f;
    __syncthreads();
    int e = k*256 + tid;
    int r = eidx[e], c = eidx[NEDGE+e];
    float a = markov[r*NNODE + c];
    ws[WS_EA+e] = a;
    atomicAdd(&sh.hi.hd[c], 1);
    atomicAdd(&sh.hi.hf[c], a);
    __syncthreads();
    ((int*)(ws+WS_DEGP))[k*512+tid]     = sh.hi.hd[tid];
    ((int*)(ws+WS_DEGP))[k*512+256+tid] = sh.hi.hd[256+tid];
    ws[WS_LSUMP + k*512+tid]     = sh.hi.hf[tid];
    ws[WS_LSUMP + k*512+256+tid] = sh.hi.hf[256+tid];
  } else if (b < 144){
    // PS/PD rows (coalesced over g2W cols)
    int j = b-128;
    const float* att = (j<8) ? g2as : g2ad;
    int h = j&7;
    float s = 0.f;
    for (int c=0;c<32;c++) s += att[h*32+c] * g2W[(h*32+c)*256 + tid];
    ws[WS_PS + j*256 + tid] = s;
  } else if (b < 208){
    // g2W transpose, 32x32 tiles
    int t2 = b-144, tr = t2>>3, tc = t2&7;
    int r0 = tid>>5, c0 = tid&31;
    for (int k=0;k<4;k++){
      int r = k*8 + r0;
      sh.tr.T[r][c0] = g2W[(tr*32+r)*256 + tc*32 + c0];
    }
    __syncthreads();
    for (int k=0;k<4;k++){
      int r = k*8 + r0;
      ws[WS_G2WT + (tc*32+r)*256 + tr*32 + c0] = sh.tr.T[c0][r];
    }
  } else if (b == 208){
    ws[WS_STOPV+tid] = 0.f; ws[WS_STOPV+256+tid] = 0.f;
    __syncthreads();
    ws[WS_STOPV + stops[tid]] = 1.0f;
    if (tid < 8){
      float s=0.f; for (int c=0;c<32;c++) s += g1We[tid*32+c]*g1ae[tid*32+c];
      ws[WS_AE+tid]=s;
    } else if (tid < 16){
      int h=tid-8; float s=0.f; for (int c=0;c<32;c++) s += g2We[h*32+c]*g2ae[h*32+c];
      ws[WS_AE+8+h]=s;
    }
  } else if (b == 209){
    ((int*)(ws+WS_CURSOR))[tid] = 0;
    ((int*)(ws+WS_CURSOR))[256+tid] = 0;
  } else if (b >= 210 && b < 274){
    int idx = (b-210)*256 + tid;
    int k = idx>>8, c = idx&255;
    ws[WS_WESF+idx] = (k<32) ? Wes[k*512+c] : Wes[(k-32)*512+256+c];
  }
  grid.sync();

  // ---------- Phase C: scan (block 0) + minmax final (block 1) ----------
  if (b == 0){
    int n0 = tid, n1 = tid+256;
    int d0=0, d1=0; float l0=0.f, l1=0.f;
    const int* dp = (const int*)(ws+WS_DEGP);
    for (int k=0;k<64;k++){
      d0 += dp[k*512+n0]; d1 += dp[k*512+n1];
      l0 += ws[WS_LSUMP+k*512+n0]; l1 += ws[WS_LSUMP+k*512+n1];
    }
    sh.sc.a[n0]=d0; sh.sc.a[n1]=d1;
    __syncthreads();
    int *src=sh.sc.a, *dst=sh.sc.b;
    for (int off=1; off<512; off<<=1){
      dst[tid]     = src[tid]     + (tid>=off ? src[tid-off] : 0);
      dst[tid+256] = src[tid+256] + (tid+256>=off ? src[tid+256-off] : 0);
      __syncthreads();
      int* tmp=src; src=dst; dst=tmp;
    }
    ((int*)(ws+WS_STARTS))[n0] = src[n0]-d0;
    ((int*)(ws+WS_STARTS))[n1] = src[n1]-d1;
    ((int*)(ws+WS_DEG))[n0] = d0;
    ((int*)(ws+WS_DEG))[n1] = d1;
    ws[WS_LATTR+n0] = l0 / (float)(d0>1 ? d0 : 1);
    ws[WS_LATTR+n1] = l1 / (float)(d1>1 ? d1 : 1);
  } else if (b == 1){
    if (tid < 64){ sh.mm.smn[tid]=ws[WS_MMP+tid]; sh.mm.smx[tid]=ws[WS_MMP+64+tid]; }
    __syncthreads();
    if (tid == 0){
      float mn=sh.mm.smn[0], mx=sh.mm.smx[0];
      for (int i=1;i<64;i++){ mn=fminf(mn,sh.mm.smn[i]); mx=fmaxf(mx,sh.mm.smx[i]); }
      ws[WS_MM]=mn; ws[WS_MM+1]=mx;
    }
  }
  grid.sync();

  // ---------- Phase D: CSR scatter (64 blocks, device atomics) ----------
  if (b < 64){
    int e = b*256 + tid;
    int c = eidx[NEDGE+e];
    int p = ((int*)(ws+WS_STARTS))[c] + atomicAdd((int*)(ws+WS_CURSOR)+c, 1);
    ((int*)(ws+WS_CSRC))[p] = eidx[e];
    ws[WS_CEA+p] = ws[WS_EA+e];
  }
  grid.sync();

  // ---------- Phase E: GAT layer-1 aggregate + h2 + logits2 ----------
  agg_phase<1>(ws+WS_H, ws+WS_ASRC, ws+WS_ADST, (const int*)(ws+WS_CSRC), ws+WS_CEA,
               (const int*)(ws+WS_STARTS), (const int*)(ws+WS_DEG), ws+WS_LATTR,
               ws+WS_AE, g1b, dist, markov, ws, b, tid, sh);
  grid.sync();

  // ---------- Phase F: GAT layer-2 aggregate + uv + packA ----------
  agg_phase<2>(ws+WS_H2, ws+WS_ASRC2, ws+WS_ADST2, (const int*)(ws+WS_CSRC), ws+WS_CEA,
               (const int*)(ws+WS_STARTS), (const int*)(ws+WS_DEG), ws+WS_LATTR,
               ws+WS_AE+8, g2b, dist, markov, ws, b, tid, sh);
  grid.sync();

  // ---------- Phase G: sk + packB + Wc2->bf16 ----------
  {
    int o = b;
    if (tid<32) sh.sk.besf[tid] = bes[tid];
    __syncthreads();
    const float* wr = Wc1 + (size_t)o*INLEN;
    const float* UV = ws + WS_UV;
    bf16* bp  = (bf16*)(ws+WS_BPACK);
    bf16* w2b = (bf16*)(ws+WS_WC2B);
    float sP = 0.f, tP = 0.f;
    for (int idx=tid; idx<16384; idx+=256){
      float wv = wr[idx];
      sP += wv;
      tP += wv * (UV[((idx>>5)<<6) + 32 + (idx&31)] + sh.sk.besf[idx&31]);
    }
    for (int j=tid; j<512; j+=256) tP += ws[WS_STOPV+j] * wr[17417+j];
    if (tid < 9){
      int g = tid/3, f = tid-g*3;
      float sv = (g==0) ? Wweek[wd[0]*3+f]
               : (g==1) ? Wcap[cp[0]*3+f]
                        : Wveh[vh[0]*3+f];
      tP += sv * wr[17408+tid];
    }
    sh.sk.red[tid] = sP; __syncthreads();
    if (tid<32){
      float s=0.f; for (int q=0;q<8;q++) s += sh.sk.red[tid+32*q];
      bp[(size_t)o*K1 + tid] = __float2bfloat16(s);
    }
    __syncthreads();
    sh.sk.red[tid] = tP; __syncthreads();
    for (int off=128; off; off>>=1){ if (tid<off) sh.sk.red[tid] += sh.sk.red[tid+off]; __syncthreads(); }
    if (tid==0) ws[WS_K+o] = sh.sk.red[0] + bc1[o];
    for (int j=tid; j<1024; j+=256)
      bp[(size_t)o*K1 + 32 + j] = __float2bfloat16(wr[16384+j]);
    for (int j=tid; j<512; j+=256)
      w2b[o*512+j] = __float2bfloat16(Wc2[o*512+j]);
  }
  grid.sync();

  // ---------- Phase H: decoder GEMM 1 (64 blocks) ----------
  if (b < 64){
    gemm_tile<true,true>((const bf16*)(ws+WS_APACK), (const bf16*)(ws+WS_BPACK),
                         ws+WS_K, nullptr, (bf16*)(ws+WS_OUT1), 512, K1,
                         (b>>3)*64, (b&7)*64, tid, sh.ge.Als, sh.ge.Bls);
  }
  grid.sync();

  // ---------- Phase I: decoder GEMM 2 (64 blocks) ----------
  if (b < 64){
    gemm_tile<false,false>((const bf16*)(ws+WS_OUT1), (const bf16*)(ws+WS_WC2B),
                           bc2, out, nullptr, 512, 512,
                           (b>>3)*64, (b&7)*64, tid, sh.ge.Als, sh.ge.Bls);
  }
}

extern "C" void kernel_launch(void* const* d_in, const int* in_sizes, int n_in,
                              void* d_out, int out_size, void* d_ws, size_t ws_size,
                              hipStream_t stream){
  const float* dist   = (const float*)d_in[0];
  const float* markov = (const float*)d_in[1];
  const float* demand = (const float*)d_in[2];
  const float* Wweek  = (const float*)d_in[3];
  const float* Wcap   = (const float*)d_in[4];
  const float* Wveh   = (const float*)d_in[5];
  const float* g1W    = (const float*)d_in[6];
  const float* g1as   = (const float*)d_in[7];
  const float* g1ad   = (const float*)d_in[8];
  const float* g1We   = (const float*)d_in[9];
  const float* g1ae   = (const float*)d_in[10];
  const float* g1b    = (const float*)d_in[11];
  const float* g2W    = (const float*)d_in[12];
  const float* g2as   = (const float*)d_in[13];
  const float* g2ad   = (const float*)d_in[14];
  const float* g2We   = (const float*)d_in[15];
  const float* g2ae   = (const float*)d_in[16];
  const float* g2b    = (const float*)d_in[17];
  const float* Wes    = (const float*)d_in[18];
  const float* bes    = (const float*)d_in[19];
  const float* Wc1    = (const float*)d_in[20];
  const float* bc1    = (const float*)d_in[21];
  const float* Wc2    = (const float*)d_in[22];
  const float* bc2    = (const float*)d_in[23];
  const int*   stops  = (const int*)d_in[24];
  const int*   eidx   = (const int*)d_in[25];
  const int*   wd     = (const int*)d_in[26];
  const int*   vh     = (const int*)d_in[27];
  const int*   cp     = (const int*)d_in[28];
  float* out = (float*)d_out;
  float* ws  = (float*)d_ws;

  void* args[] = { &dist,&markov,&demand,&Wweek,&Wcap,&Wveh,&g1W,&g1as,&g1ad,&g1We,&g1ae,&g1b,
                   &g2W,&g2as,&g2ad,&g2We,&g2ae,&g2b,&Wes,&bes,&Wc1,&bc1,&Wc2,&bc2,
                   &stops,&eidx,&wd,&vh,&cp,&out,&ws };
  hipLaunchCooperativeKernel((void*)mega, dim3(512), dim3(256), args, 0, stream);
}

// Round 8
// 236.069 us; speedup vs baseline: 2.7986x; 2.7986x over previous
//
#include <hip/hip_runtime.h>
#include <hip/hip_bf16.h>

typedef __hip_bfloat16 bf16;
typedef __attribute__((ext_vector_type(8))) short bf16x8;
typedef __attribute__((ext_vector_type(4))) float f32x4;

#define NNODE 512
#define NEDGE 16384
#define INLEN 17929
#define K1    1056

// ---- workspace layout (offsets in floats) ----
#define WS_EA      0         // 16384
#define WS_CSRC    16384     // 16384 (int)
#define WS_CEA     32768     // 16384
#define WS_DEG     49152     // 512 (int)
#define WS_STARTS  49664     // 512 (int)
#define WS_LATTR   50176     // 512
#define WS_MM      50688     // 2
#define WS_MMP     50690     // 128
#define WS_STOPV   50818     // 512
#define WS_AE      51330     // 16
#define WS_PS      51346     // 4096
#define WS_H       55552     // 512*256
#define WS_G2WT    186624    // 256*256
#define WS_H2      317696    // 512*256
#define WS_ASRC    448768    // 512*8
#define WS_ADST    452864    // 512*8
#define WS_UV      456960    // 512*64
#define WS_K       489728    // 512
#define WS_APACK   490240    // bf16 512*1056 -> 270336 floats
#define WS_BPACK   760576    // bf16 512*1056 -> 270336 floats
#define WS_OUT1    1030912   // bf16 512*512  -> 131072 floats
#define WS_WC2B    1161984   // bf16 512*512  -> 131072 floats
#define WS_WESF    1293056   // 64*256
#define WS_ASRC2   1309440   // 512*8
#define WS_ADST2   1313536   // 512*8
#define WS_CURSOR  1317632   // 512 (int)
#define WS_DEGP    1318144   // 64*512 (int)
#define WS_LSUMP   1350912   // 64*512
// end = 1383680 floats ≈ 5.5 MB

// ============ K1: fused prep (all input-only, fully parallel) ===============
// b<512: layer-1 h + logits | b==512: stopv + AE dots | b 513-514: wes pack
// b 515-578: minmax partials | b 579-642: ea gather + partial histogram
// b 643-658: PS/PD | b 659-674: g2W transpose | b==675: cursor zero
__global__ __launch_bounds__(256)
void k_prep(const float* __restrict__ demand, const float* __restrict__ W1,
            const float* __restrict__ att_s, const float* __restrict__ att_d,
            const int* __restrict__ stops, const float* __restrict__ Wes,
            const float* __restrict__ dist, const float* __restrict__ markov,
            const int* __restrict__ eidx,
            const float* __restrict__ g1We, const float* __restrict__ g1ae,
            const float* __restrict__ g2We, const float* __restrict__ g2ae,
            const float* __restrict__ g2W,  const float* __restrict__ g2as,
            const float* __restrict__ g2ad, float* ws){
  int b = blockIdx.x, tid = threadIdx.x;
  if (b < 512){
    int hd = tid>>5, c = tid&31;
    float hv = demand[b] * W1[tid];
    ws[WS_H + b*256 + tid] = hv;
    float ps = hv * att_s[tid];
    float pd = hv * att_d[tid];
    for (int off=16; off; off>>=1){ ps += __shfl_down(ps,off,32); pd += __shfl_down(pd,off,32); }
    if (c==0){ ws[WS_ASRC + b*8+hd]=ps; ws[WS_ADST + b*8+hd]=pd; }
  } else if (b == 512){
    ws[WS_STOPV+tid] = 0.f; ws[WS_STOPV+256+tid] = 0.f;
    __syncthreads();
    ws[WS_STOPV + stops[tid]] = 1.0f;
    if (tid < 8){
      float s=0.f; for (int c=0;c<32;c++) s += g1We[tid*32+c]*g1ae[tid*32+c];
      ws[WS_AE+tid]=s;
    } else if (tid < 16){
      int h=tid-8; float s=0.f; for (int c=0;c<32;c++) s += g2We[h*32+c]*g2ae[h*32+c];
      ws[WS_AE+8+h]=s;
    }
  } else if (b < 515){
    for (int idx = (b-513)*8192 + tid; idx < (b-512)*8192; idx += 256){
      int k = idx>>8, c = idx&255;
      ws[WS_WESF+idx] = (k<32) ? Wes[k*512+c] : Wes[(k-32)*512+256+c];
    }
  } else if (b < 579){
    __shared__ float smn[256], smx[256];
    int p = b-515;
    float mn = 3.4e38f, mx = -3.4e38f;
    for (int k=0;k<16;k++){
      float v = dist[p*4096 + k*256 + tid];
      mn = fminf(mn,v); mx = fmaxf(mx,v);
    }
    smn[tid]=mn; smx[tid]=mx; __syncthreads();
    for (int off=128; off; off>>=1){
      if (tid<off){ smn[tid]=fminf(smn[tid],smn[tid+off]); smx[tid]=fmaxf(smx[tid],smx[tid+off]); }
      __syncthreads();
    }
    if (tid==0){ ws[WS_MMP+p]=smn[0]; ws[WS_MMP+64+p]=smx[0]; }
  } else if (b < 643){
    // ea gather + per-block partial histogram (LDS, no global atomics)
    __shared__ int   hd_[512];
    __shared__ float hf_[512];
    int k = b-579;
    hd_[tid]=0; hd_[256+tid]=0; hf_[tid]=0.f; hf_[256+tid]=0.f;
    __syncthreads();
    int e = k*256 + tid;
    int r = eidx[e], c = eidx[NEDGE+e];
    float a = markov[r*NNODE + c];
    ws[WS_EA+e] = a;
    atomicAdd(&hd_[c], 1);
    atomicAdd(&hf_[c], a);
    __syncthreads();
    ((int*)(ws+WS_DEGP))[k*512+tid]     = hd_[tid];
    ((int*)(ws+WS_DEGP))[k*512+256+tid] = hd_[256+tid];
    ws[WS_LSUMP + k*512+tid]     = hf_[tid];
    ws[WS_LSUMP + k*512+256+tid] = hf_[256+tid];
  } else if (b < 659){
    int j = b-643;
    const float* att = (j<8) ? g2as : g2ad;
    int h = j&7;
    float s = 0.f;
    for (int c=0;c<32;c++) s += att[h*32+c] * g2W[(h*32+c)*256 + tid];
    ws[WS_PS + j*256 + tid] = s;
  } else if (b < 675){
    __shared__ float T[64][65];
    int tb = b-659, tr = tb>>2, tc = tb&3;
    int w = tid>>6, c = tid&63;
    for (int k=0;k<16;k++){
      int r = k*4 + w;
      T[r][c] = g2W[(tr*64+r)*256 + tc*64 + c];
    }
    __syncthreads();
    for (int k=0;k<16;k++){
      int r = k*4 + w;
      ws[WS_G2WT + (tc*64+r)*256 + tr*64 + c] = T[c][r];
    }
  } else {
    ((int*)(ws+WS_CURSOR))[tid] = 0;
    ((int*)(ws+WS_CURSOR))[256+tid] = 0;
  }
}

// ============ K2: scan (1 block, 512 thr): partial sums -> deg/starts/lattr =
__global__ __launch_bounds__(512)
void k_scan(float* ws){
  __shared__ int sc[512];
  __shared__ float rmn[64], rmx[64];
  int t = threadIdx.x;
  if (t < 64){ rmn[t]=ws[WS_MMP+t]; rmx[t]=ws[WS_MMP+64+t]; }
  __syncthreads();
  if (t < 32){ rmn[t]=fminf(rmn[t],rmn[t+32]); rmx[t]=fmaxf(rmx[t],rmx[t+32]); }
  __syncthreads();
  if (t == 0){
    float mn=rmn[0], mx=rmx[0];
    for (int i=1;i<32;i++){ mn=fminf(mn,rmn[i]); mx=fmaxf(mx,rmx[i]); }
    ws[WS_MM]=mn; ws[WS_MM+1]=mx;
  }
  const int* dp = (const int*)(ws+WS_DEGP);
  int d = 0; float l = 0.f;
  for (int k=0;k<64;k++){
    d += dp[k*512+t];
    l += ws[WS_LSUMP+k*512+t];
  }
  sc[t] = d; __syncthreads();
  for (int off=1; off<512; off<<=1){
    int v = (t>=off) ? sc[t-off] : 0; __syncthreads();
    sc[t] += v; __syncthreads();
  }
  ((int*)(ws+WS_STARTS))[t] = sc[t]-d;
  ((int*)(ws+WS_DEG))[t] = d;
  ws[WS_LATTR+t] = l / (float)(d>1 ? d : 1);
}

// ============ K3: CSR scatter (64 blocks, global atomic cursors) ============
__global__ __launch_bounds__(256)
void k_scatter(const int* __restrict__ eidx, float* ws){
  int e = blockIdx.x*256 + threadIdx.x;
  int c = eidx[NEDGE+e];
  int p = ((int*)(ws+WS_STARTS))[c] + atomicAdd((int*)(ws+WS_CURSOR)+c, 1);
  ((int*)(ws+WS_CSRC))[p] = eidx[e];
  ws[WS_CEA+p] = ws[WS_EA+e];
}

// ============ GAT aggregate; MODE 1: +h2+logits2 epi, MODE 2: +uv+packA epi =
template<int MODE>
__global__ __launch_bounds__(256)
void k_agg(const float* __restrict__ hbuf, const float* __restrict__ asrc,
           const float* __restrict__ adst, const int* __restrict__ csrc,
           const float* __restrict__ cea, const int* __restrict__ starts,
           const int* __restrict__ deg, const float* __restrict__ lattr,
           const float* __restrict__ AEp, const float* __restrict__ bvec,
           const float* __restrict__ dist, const float* __restrict__ markov,
           float* ws){
  int t = blockIdx.x, tid = threadIdx.x, hd = tid>>5;
  __shared__ float AE[8], m[8], den[8], alpha[8];
  __shared__ float L[32*8];
  __shared__ float xrow[256];
  __shared__ float uvrow[64];
  if (tid < 8) AE[tid] = AEp[tid];
  __syncthreads();
  int d = deg[t], s0 = starts[t];
  if (tid < 8){
    float aself = asrc[t*8+tid] + adst[t*8+tid] + lattr[t]*AE[tid];
    aself = aself>=0.f ? aself : 0.2f*aself;
    m[tid] = aself; den[tid] = 1.0f;
  }
  __syncthreads();
  float acc = hbuf[t*256+tid];
  int el = tid>>3, h2i = tid&7;
  float adt2 = adst[t*8+h2i], ae2 = AE[h2i];
  for (int e0=0; e0<d; e0+=32){
    int ce = d-e0 < 32 ? d-e0 : 32;
    float lg = -3.4e38f;
    if (el < ce){
      int src = csrc[s0+e0+el];
      float a = asrc[src*8+h2i] + adt2 + cea[s0+e0+el]*ae2;
      lg = a>=0.f ? a : 0.2f*a;
    }
    L[el*8+h2i] = lg;
    __syncthreads();
    if (tid < 8){
      float mm = m[tid];
      for (int e=0;e<ce;e++) mm = fmaxf(mm, L[e*8+tid]);
      float al = __expf(m[tid]-mm);
      float dd = den[tid]*al;
      for (int e=0;e<ce;e++) dd += __expf(L[e*8+tid]-mm);
      m[tid]=mm; den[tid]=dd; alpha[tid]=al;
    }
    __syncthreads();
    if (el < ce) L[el*8+h2i] = __expf(lg - m[h2i]);
    __syncthreads();
    acc *= alpha[hd];
    for (int e=0;e<ce;e++){
      int sre = csrc[s0+e0+e];
      acc += L[e*8+hd] * hbuf[sre*256+tid];
    }
    __syncthreads();
  }
  float v = fmaxf(acc/den[hd] + bvec[tid], 0.f);
  xrow[tid] = v;
  __syncthreads();
  if (MODE == 1){
    const float* g2wt = ws + WS_G2WT;
    float hr = 0.f;
    for (int c=0;c<256;c++) hr += xrow[c] * g2wt[c*256 + tid];
    ws[WS_H2 + t*256 + tid] = hr;
    if (tid < 64){
      int j = tid>>2, q = tid&3;
      const float* pr = ws + WS_PS + j*256 + q*64;
      const float* xr = xrow + q*64;
      float p = 0.f;
      for (int c=0;c<64;c++) p += xr[c]*pr[c];
      p += __shfl_down(p,2,4);
      p += __shfl_down(p,1,4);
      if (q==0){
        if (j<8) ws[WS_ASRC2 + t*8+j] = p;
        else     ws[WS_ADST2 + t*8+(j-8)] = p;
      }
    }
  } else {
    int k = tid>>2, q = tid&3;
    const float* wr = ws + WS_WESF + k*256 + q*64;
    const float* xr = xrow + q*64;
    float p = 0.f;
    for (int c=0;c<64;c++) p += xr[c]*wr[c];
    p += __shfl_down(p,2,4);
    p += __shfl_down(p,1,4);
    if (q==0){ ws[WS_UV + t*64+k] = p; uvrow[k] = p; }
    __syncthreads();
    float mn = ws[WS_MM], mx = ws[WS_MM+1];
    float inv = 1.0f/(mx-mn);
    bf16* ap = (bf16*)(ws+WS_APACK);
    for (int j=tid; j<K1; j+=256){
      float v2;
      if (j<32)       v2 = uvrow[j];
      else if (j<544) v2 = (dist[t*512 + j-32] - mn) * inv;
      else            v2 = markov[t*512 + j-544];
      ap[(size_t)t*K1 + j] = __float2bfloat16(v2);
    }
  }
}

// ============ K6: fused sk+packB + Wc2->bf16 ================================
__global__ __launch_bounds__(256)
void k_skpack(const float* __restrict__ Wc1, const float* __restrict__ bc1,
              const float* __restrict__ bes, const float* __restrict__ Wweek,
              const float* __restrict__ Wcap, const float* __restrict__ Wveh,
              const int* __restrict__ wd, const int* __restrict__ vh,
              const int* __restrict__ cp, const float* __restrict__ Wc2,
              float* ws){
  int o = blockIdx.x, tid = threadIdx.x;
  __shared__ float besf[32];
  __shared__ float red[256];
  if (tid<32) besf[tid] = bes[tid];
  __syncthreads();
  const float* wr = Wc1 + (size_t)o*INLEN;
  const float* UV = ws + WS_UV;
  bf16* bp  = (bf16*)(ws+WS_BPACK);
  bf16* w2b = (bf16*)(ws+WS_WC2B);
  float sP = 0.f, tP = 0.f;
  for (int idx=tid; idx<16384; idx+=256){
    float wv = wr[idx];
    sP += wv;
    tP += wv * (UV[((idx>>5)<<6) + 32 + (idx&31)] + besf[idx&31]);
  }
  for (int j=tid; j<512; j+=256) tP += ws[WS_STOPV+j] * wr[17417+j];
  if (tid < 9){
    int g = tid/3, f = tid-g*3;
    float sv = (g==0) ? Wweek[wd[0]*3+f]
             : (g==1) ? Wcap[cp[0]*3+f]
                      : Wveh[vh[0]*3+f];
    tP += sv * wr[17408+tid];
  }
  red[tid] = sP; __syncthreads();
  if (tid<32){
    float s=0.f; for (int q=0;q<8;q++) s += red[tid+32*q];
    bp[(size_t)o*K1 + tid] = __float2bfloat16(s);
  }
  __syncthreads();
  red[tid] = tP; __syncthreads();
  for (int off=128; off; off>>=1){ if (tid<off) red[tid] += red[tid+off]; __syncthreads(); }
  if (tid==0) ws[WS_K+o] = red[0] + bc1[o];
  for (int j=tid; j<1024; j+=256)
    bp[(size_t)o*K1 + 32 + j] = __float2bfloat16(wr[16384+j]);
  for (int j=tid; j<512; j+=256)
    w2b[o*512+j] = __float2bfloat16(Wc2[o*512+j]);
}

// ============ bf16 MFMA GEMM: C = A(MxK)·B(NxK)^T, 64x64 tile ==============
template<bool RELU, bool BF16OUT>
__global__ __launch_bounds__(256)
void gemm_mfma(const bf16* __restrict__ A, const bf16* __restrict__ B,
               const float* __restrict__ bias, float* __restrict__ Cf,
               bf16* __restrict__ Cb, int M, int N, int K){
  __shared__ short Als[2048];
  __shared__ short Bls[2048];
  const int tid = threadIdx.x;
  const int bm = blockIdx.y*64, bn = blockIdx.x*64;
  const int wave = tid>>6, lane = tid&63;
  const int wm = wave>>1, wn = wave&1;
  const int r = lane&15, q = lane>>4;
  f32x4 acc[2][2] = {};
  const int lrow = tid>>2, lq = tid&3;
  const bf16* Ag = A + (size_t)(bm+lrow)*K + lq*8;
  const bf16* Bg = B + (size_t)(bn+lrow)*K + lq*8;
  const int sidx = (lq*64+lrow)*8;
  for (int k0=0; k0<K; k0+=32){
    float4 av = *(const float4*)(Ag + k0);
    float4 bv = *(const float4*)(Bg + k0);
    *(float4*)(&Als[sidx]) = av;
    *(float4*)(&Bls[sidx]) = bv;
    __syncthreads();
    #pragma unroll
    for (int i=0;i<2;i++){
      bf16x8 af = *(const bf16x8*)(&Als[(q*64 + wm*32 + i*16 + r)*8]);
      #pragma unroll
      for (int j=0;j<2;j++){
        bf16x8 bfr = *(const bf16x8*)(&Bls[(q*64 + wn*32 + j*16 + r)*8]);
        acc[i][j] = __builtin_amdgcn_mfma_f32_16x16x32_bf16(af, bfr, acc[i][j], 0,0,0);
      }
    }
    __syncthreads();
  }
  #pragma unroll
  for (int i=0;i<2;i++){
    int row = bm + wm*32 + i*16 + q*4;
    #pragma unroll
    for (int j=0;j<2;j++){
      int col = bn + wn*32 + j*16 + r;
      float bi = bias ? bias[col] : 0.f;
      #pragma unroll
      for (int g=0; g<4; g++){
        float v = acc[i][j][g] + bi;
        if (RELU) v = fmaxf(v, 0.f);
        if (BF16OUT) Cb[(size_t)(row+g)*N + col] = __float2bfloat16(v);
        else         Cf[(size_t)(row+g)*N + col] = v;
      }
    }
  }
}

extern "C" void kernel_launch(void* const* d_in, const int* in_sizes, int n_in,
                              void* d_out, int out_size, void* d_ws, size_t ws_size,
                              hipStream_t stream){
  const float* dist   = (const float*)d_in[0];
  const float* markov = (const float*)d_in[1];
  const float* demand = (const float*)d_in[2];
  const float* Wweek  = (const float*)d_in[3];
  const float* Wcap   = (const float*)d_in[4];
  const float* Wveh   = (const float*)d_in[5];
  const float* g1W    = (const float*)d_in[6];
  const float* g1as   = (const float*)d_in[7];
  const float* g1ad   = (const float*)d_in[8];
  const float* g1We   = (const float*)d_in[9];
  const float* g1ae   = (const float*)d_in[10];
  const float* g1b    = (const float*)d_in[11];
  const float* g2W    = (const float*)d_in[12];
  const float* g2as   = (const float*)d_in[13];
  const float* g2ad   = (const float*)d_in[14];
  const float* g2We   = (const float*)d_in[15];
  const float* g2ae   = (const float*)d_in[16];
  const float* g2b    = (const float*)d_in[17];
  const float* Wes    = (const float*)d_in[18];
  const float* bes    = (const float*)d_in[19];
  const float* Wc1    = (const float*)d_in[20];
  const float* bc1    = (const float*)d_in[21];
  const float* Wc2    = (const float*)d_in[22];
  const float* bc2    = (const float*)d_in[23];
  const int*   stops  = (const int*)d_in[24];
  const int*   eidx   = (const int*)d_in[25];
  const int*   wd     = (const int*)d_in[26];
  const int*   vh     = (const int*)d_in[27];
  const int*   cp     = (const int*)d_in[28];
  float* out = (float*)d_out;
  float* ws = (float*)d_ws;

  const int*   csrc   = (const int*)(ws+WS_CSRC);
  const float* cea    = ws+WS_CEA;
  const int*   starts = (const int*)(ws+WS_STARTS);
  const int*   deg    = (const int*)(ws+WS_DEG);
  const float* lattr  = ws+WS_LATTR;

  // K1: all input-only prep (+ histogram partials, cursor zero)
  k_prep<<<676,256,0,stream>>>(demand, g1W, g1as, g1ad, stops, Wes, dist, markov, eidx,
                               g1We, g1ae, g2We, g2ae, g2W, g2as, g2ad, ws);
  // K2: scan of histogram partials (1 small block)
  k_scan<<<1,512,0,stream>>>(ws);
  // K3: CSR scatter (64 blocks)
  k_scatter<<<64,256,0,stream>>>(eidx, ws);
  // K4: GAT layer-1 aggregate + h2 + logits-2 epilogue
  k_agg<1><<<512,256,0,stream>>>(ws+WS_H, ws+WS_ASRC, ws+WS_ADST, csrc, cea, starts, deg,
                                 lattr, ws+WS_AE, g1b, dist, markov, ws);
  // K5: GAT layer-2 aggregate + uv + packA epilogue
  k_agg<2><<<512,256,0,stream>>>(ws+WS_H2, ws+WS_ASRC2, ws+WS_ADST2, csrc, cea, starts, deg,
                                 lattr, ws+WS_AE+8, g2b, dist, markov, ws);
  // K6: sk + packB + Wc2->bf16
  k_skpack<<<512,256,0,stream>>>(Wc1, bc1, bes, Wweek, Wcap, Wveh, wd, vh, cp, Wc2, ws);
  // K7/K8: decoder MFMA GEMMs
  gemm_mfma<true,true><<<dim3(8,8),256,0,stream>>>((const bf16*)(ws+WS_APACK), (const bf16*)(ws+WS_BPACK),
                                                   ws+WS_K, nullptr, (bf16*)(ws+WS_OUT1), 512, 512, K1);
  gemm_mfma<false,false><<<dim3(8,8),256,0,stream>>>((const bf16*)(ws+WS_OUT1), (const bf16*)(ws+WS_WC2B),
                                                     bc2, out, nullptr, 512, 512, 512);
}

// Round 9
// 212.764 us; speedup vs baseline: 3.1051x; 1.1095x over previous
//
#include <hip/hip_runtime.h>
#include <hip/hip_bf16.h>

typedef __hip_bfloat16 bf16;
typedef __attribute__((ext_vector_type(8))) short bf16x8;
typedef __attribute__((ext_vector_type(4))) float f32x4;

#define NNODE 512
#define NEDGE 16384
#define INLEN 17929
#define K1    1056

// ---- workspace layout (offsets in floats) ----
#define WS_EA      0         // 16384
#define WS_CSRC    16384     // 16384 (int)
#define WS_CEA     32768     // 16384
#define WS_DEG     49152     // 512 (int)
#define WS_STARTS  49664     // 512 (int)
#define WS_LATTR   50176     // 512
#define WS_MM      50688     // 2
#define WS_MMP     50690     // 128
#define WS_STOPV   50818     // 512
#define WS_AE      51330     // 16
#define WS_PS      51346     // 4096
#define WS_H       55552     // 512*256
#define WS_G2WT    186624    // 256*256
#define WS_H2      317696    // 512*256
#define WS_ASRC    448768    // 512*8
#define WS_ADST    452864    // 512*8
#define WS_UV      456960    // 512*64
#define WS_K       489728    // 512
#define WS_APACK   490240    // bf16 512*1056 -> 270336 floats
#define WS_BPACK   760576    // bf16 512*1056 -> 270336 floats
#define WS_OUT1    1030912   // bf16 512*512  -> 131072 floats
#define WS_WC2B    1161984   // bf16 512*512  -> 131072 floats
#define WS_WESF    1293056   // 64*256
#define WS_ASRC2   1309440   // 512*8
#define WS_ADST2   1313536   // 512*8
#define WS_CURSOR  1317632   // 512 (int)
#define WS_DEGP    1318144   // 64*512 (int)
#define WS_LSUMP   1350912   // 64*512
// end = 1383680 floats ≈ 5.5 MB

// ============ K1: fused prep (all input-only, fully parallel) ===============
__global__ __launch_bounds__(256)
void k_prep(const float* __restrict__ demand, const float* __restrict__ W1,
            const float* __restrict__ att_s, const float* __restrict__ att_d,
            const int* __restrict__ stops, const float* __restrict__ Wes,
            const float* __restrict__ dist, const float* __restrict__ markov,
            const int* __restrict__ eidx,
            const float* __restrict__ g1We, const float* __restrict__ g1ae,
            const float* __restrict__ g2We, const float* __restrict__ g2ae,
            const float* __restrict__ g2W,  const float* __restrict__ g2as,
            const float* __restrict__ g2ad, float* ws){
  int b = blockIdx.x, tid = threadIdx.x;
  if (b < 512){
    int hd = tid>>5, c = tid&31;
    float hv = demand[b] * W1[tid];
    ws[WS_H + b*256 + tid] = hv;
    float ps = hv * att_s[tid];
    float pd = hv * att_d[tid];
    for (int off=16; off; off>>=1){ ps += __shfl_down(ps,off,32); pd += __shfl_down(pd,off,32); }
    if (c==0){ ws[WS_ASRC + b*8+hd]=ps; ws[WS_ADST + b*8+hd]=pd; }
  } else if (b == 512){
    ws[WS_STOPV+tid] = 0.f; ws[WS_STOPV+256+tid] = 0.f;
    __syncthreads();
    ws[WS_STOPV + stops[tid]] = 1.0f;
    if (tid < 8){
      float s=0.f; for (int c=0;c<32;c++) s += g1We[tid*32+c]*g1ae[tid*32+c];
      ws[WS_AE+tid]=s;
    } else if (tid < 16){
      int h=tid-8; float s=0.f; for (int c=0;c<32;c++) s += g2We[h*32+c]*g2ae[h*32+c];
      ws[WS_AE+8+h]=s;
    }
  } else if (b < 515){
    for (int idx = (b-513)*8192 + tid; idx < (b-512)*8192; idx += 256){
      int k = idx>>8, c = idx&255;
      ws[WS_WESF+idx] = (k<32) ? Wes[k*512+c] : Wes[(k-32)*512+256+c];
    }
  } else if (b < 579){
    __shared__ float smn[256], smx[256];
    int p = b-515;
    float mn = 3.4e38f, mx = -3.4e38f;
    for (int k=0;k<16;k++){
      float v = dist[p*4096 + k*256 + tid];
      mn = fminf(mn,v); mx = fmaxf(mx,v);
    }
    smn[tid]=mn; smx[tid]=mx; __syncthreads();
    for (int off=128; off; off>>=1){
      if (tid<off){ smn[tid]=fminf(smn[tid],smn[tid+off]); smx[tid]=fmaxf(smx[tid],smx[tid+off]); }
      __syncthreads();
    }
    if (tid==0){ ws[WS_MMP+p]=smn[0]; ws[WS_MMP+64+p]=smx[0]; }
  } else if (b < 643){
    __shared__ int   hd_[512];
    __shared__ float hf_[512];
    int k = b-579;
    hd_[tid]=0; hd_[256+tid]=0; hf_[tid]=0.f; hf_[256+tid]=0.f;
    __syncthreads();
    int e = k*256 + tid;
    int r = eidx[e], c = eidx[NEDGE+e];
    float a = markov[r*NNODE + c];
    ws[WS_EA+e] = a;
    atomicAdd(&hd_[c], 1);
    atomicAdd(&hf_[c], a);
    __syncthreads();
    ((int*)(ws+WS_DEGP))[k*512+tid]     = hd_[tid];
    ((int*)(ws+WS_DEGP))[k*512+256+tid] = hd_[256+tid];
    ws[WS_LSUMP + k*512+tid]     = hf_[tid];
    ws[WS_LSUMP + k*512+256+tid] = hf_[256+tid];
  } else if (b < 659){
    int j = b-643;
    const float* att = (j<8) ? g2as : g2ad;
    int h = j&7;
    float s = 0.f;
    for (int c=0;c<32;c++) s += att[h*32+c] * g2W[(h*32+c)*256 + tid];
    ws[WS_PS + j*256 + tid] = s;
  } else if (b < 675){
    __shared__ float T[64][65];
    int tb = b-659, tr = tb>>2, tc = tb&3;
    int w = tid>>6, c = tid&63;
    for (int k=0;k<16;k++){
      int r = k*4 + w;
      T[r][c] = g2W[(tr*64+r)*256 + tc*64 + c];
    }
    __syncthreads();
    for (int k=0;k<16;k++){
      int r = k*4 + w;
      ws[WS_G2WT + (tc*64+r)*256 + tr*64 + c] = T[c][r];
    }
  } else {
    ((int*)(ws+WS_CURSOR))[tid] = 0;
    ((int*)(ws+WS_CURSOR))[256+tid] = 0;
  }
}

// ============ K2: merged scan + scatter (32 blocks x 512 thr) ===============
// Every block redundantly computes deg-sum + exclusive scan in LDS (same wall
// time as one block); block 0 additionally writes DEG/STARTS/LATTR + minmax.
__global__ __launch_bounds__(512)
void k_scansc(const int* __restrict__ eidx, float* ws){
  __shared__ int sc[512];
  __shared__ int startS[512];
  __shared__ float rmn[64], rmx[64];
  int t = threadIdx.x, b = blockIdx.x;
  const int* dp = (const int*)(ws+WS_DEGP);
  int d = 0;
  for (int k=0;k<64;k++) d += dp[k*512+t];
  sc[t] = d; __syncthreads();
  for (int off=1; off<512; off<<=1){
    int v = (t>=off) ? sc[t-off] : 0; __syncthreads();
    sc[t] += v; __syncthreads();
  }
  startS[t] = sc[t]-d;
  if (b == 0){
    float l = 0.f;
    for (int k=0;k<64;k++) l += ws[WS_LSUMP+k*512+t];
    ((int*)(ws+WS_STARTS))[t] = startS[t];
    ((int*)(ws+WS_DEG))[t] = d;
    ws[WS_LATTR+t] = l / (float)(d>1 ? d : 1);
    if (t < 64){ rmn[t]=ws[WS_MMP+t]; rmx[t]=ws[WS_MMP+64+t]; }
    __syncthreads();
    if (t == 0){
      float mn=rmn[0], mx=rmx[0];
      for (int i=1;i<64;i++){ mn=fminf(mn,rmn[i]); mx=fmaxf(mx,rmx[i]); }
      ws[WS_MM]=mn; ws[WS_MM+1]=mx;
    }
  }
  __syncthreads();
  // scatter this block's 512 edges
  int e = b*512 + t;
  int c = eidx[NEDGE+e];
  int p = startS[c] + atomicAdd((int*)(ws+WS_CURSOR)+c, 1);
  ((int*)(ws+WS_CSRC))[p] = eidx[e];
  ws[WS_CEA+p] = ws[WS_EA+e];
}

// ============ GAT aggregate; MODE 1: +h2+logits2 epi, MODE 2: +uv+packA epi =
template<int MODE>
__global__ __launch_bounds__(256)
void k_agg(const float* __restrict__ hbuf, const float* __restrict__ asrc,
           const float* __restrict__ adst, const int* __restrict__ csrc,
           const float* __restrict__ cea, const int* __restrict__ starts,
           const int* __restrict__ deg, const float* __restrict__ lattr,
           const float* __restrict__ AEp, const float* __restrict__ bvec,
           const float* __restrict__ dist, const float* __restrict__ markov,
           float* ws){
  int t = blockIdx.x, tid = threadIdx.x, hd = tid>>5;
  __shared__ float AE[8], m[8], den[8], alpha[8];
  __shared__ float L[32*8];
  __shared__ float xrow[256];
  __shared__ float uvrow[64];
  if (tid < 8) AE[tid] = AEp[tid];
  __syncthreads();
  int d = deg[t], s0 = starts[t];
  if (tid < 8){
    float aself = asrc[t*8+tid] + adst[t*8+tid] + lattr[t]*AE[tid];
    aself = aself>=0.f ? aself : 0.2f*aself;
    m[tid] = aself; den[tid] = 1.0f;
  }
  __syncthreads();
  float acc = hbuf[t*256+tid];
  int el = tid>>3, h2i = tid&7;
  float adt2 = adst[t*8+h2i], ae2 = AE[h2i];
  for (int e0=0; e0<d; e0+=32){
    int ce = d-e0 < 32 ? d-e0 : 32;
    float lg = -3.4e38f;
    if (el < ce){
      int src = csrc[s0+e0+el];
      float a = asrc[src*8+h2i] + adt2 + cea[s0+e0+el]*ae2;
      lg = a>=0.f ? a : 0.2f*a;
    }
    L[el*8+h2i] = lg;
    __syncthreads();
    if (tid < 8){
      float mm = m[tid];
      for (int e=0;e<ce;e++) mm = fmaxf(mm, L[e*8+tid]);
      float al = __expf(m[tid]-mm);
      float dd = den[tid]*al;
      for (int e=0;e<ce;e++) dd += __expf(L[e*8+tid]-mm);
      m[tid]=mm; den[tid]=dd; alpha[tid]=al;
    }
    __syncthreads();
    if (el < ce) L[el*8+h2i] = __expf(lg - m[h2i]);
    __syncthreads();
    acc *= alpha[hd];
    for (int e=0;e<ce;e++){
      int sre = csrc[s0+e0+e];
      acc += L[e*8+hd] * hbuf[sre*256+tid];
    }
    __syncthreads();
  }
  float v = fmaxf(acc/den[hd] + bvec[tid], 0.f);
  xrow[tid] = v;
  __syncthreads();
  if (MODE == 1){
    const float* g2wt = ws + WS_G2WT;
    float hr = 0.f;
    for (int c=0;c<256;c++) hr += xrow[c] * g2wt[c*256 + tid];
    ws[WS_H2 + t*256 + tid] = hr;
    if (tid < 64){
      int j = tid>>2, q = tid&3;
      const float* pr = ws + WS_PS + j*256 + q*64;
      const float* xr = xrow + q*64;
      float p = 0.f;
      for (int c=0;c<64;c++) p += xr[c]*pr[c];
      p += __shfl_down(p,2,4);
      p += __shfl_down(p,1,4);
      if (q==0){
        if (j<8) ws[WS_ASRC2 + t*8+j] = p;
        else     ws[WS_ADST2 + t*8+(j-8)] = p;
      }
    }
  } else {
    int k = tid>>2, q = tid&3;
    const float* wr = ws + WS_WESF + k*256 + q*64;
    const float* xr = xrow + q*64;
    float p = 0.f;
    for (int c=0;c<64;c++) p += xr[c]*wr[c];
    p += __shfl_down(p,2,4);
    p += __shfl_down(p,1,4);
    if (q==0){ ws[WS_UV + t*64+k] = p; uvrow[k] = p; }
    __syncthreads();
    float mn = ws[WS_MM], mx = ws[WS_MM+1];
    float inv = 1.0f/(mx-mn);
    bf16* ap = (bf16*)(ws+WS_APACK);
    for (int j=tid; j<K1; j+=256){
      float v2;
      if (j<32)       v2 = uvrow[j];
      else if (j<544) v2 = (dist[t*512 + j-32] - mn) * inv;
      else            v2 = markov[t*512 + j-544];
      ap[(size_t)t*K1 + j] = __float2bfloat16(v2);
    }
  }
}

// ============ K5: sk+packB + Wc2->bf16 — 1024 thr, 4-way ILP ================
__global__ __launch_bounds__(1024)
void k_skpack(const float* __restrict__ Wc1, const float* __restrict__ bc1,
              const float* __restrict__ bes, const float* __restrict__ Wweek,
              const float* __restrict__ Wcap, const float* __restrict__ Wveh,
              const int* __restrict__ wd, const int* __restrict__ vh,
              const int* __restrict__ cp, const float* __restrict__ Wc2,
              float* ws){
  int o = blockIdx.x, tid = threadIdx.x;
  __shared__ float besf[32];
  __shared__ float red[1024];
  if (tid<32) besf[tid] = bes[tid];
  __syncthreads();
  const float* wr = Wc1 + (size_t)o*INLEN;
  bf16* bp  = (bf16*)(ws+WS_BPACK);
  bf16* w2b = (bf16*)(ws+WS_WC2B);
  // lane is fixed across iterations (stride 1024 ≡ 0 mod 32)
  float be = besf[tid&31];
  const float* uvp = ws + WS_UV + ((tid>>5)<<6) + 32 + (tid&31);
  float sP = 0.f, tP0=0.f, tP1=0.f, tP2=0.f, tP3=0.f;
  #pragma unroll
  for (int i=0;i<16;i+=4){
    float w0 = wr[tid + 1024*(i+0)];
    float w1 = wr[tid + 1024*(i+1)];
    float w2 = wr[tid + 1024*(i+2)];
    float w3 = wr[tid + 1024*(i+3)];
    float u0 = uvp[2048*(i+0)];
    float u1 = uvp[2048*(i+1)];
    float u2 = uvp[2048*(i+2)];
    float u3 = uvp[2048*(i+3)];
    sP += (w0+w1)+(w2+w3);
    tP0 += w0*(u0+be);
    tP1 += w1*(u1+be);
    tP2 += w2*(u2+be);
    tP3 += w3*(u3+be);
  }
  float tP = (tP0+tP1)+(tP2+tP3);
  if (tid < 512) tP += ws[WS_STOPV+tid] * wr[17417+tid];
  if (tid < 9){
    int g = tid/3, f = tid-g*3;
    float sv = (g==0) ? Wweek[wd[0]*3+f]
             : (g==1) ? Wcap[cp[0]*3+f]
                      : Wveh[vh[0]*3+f];
    tP += sv * wr[17408+tid];
  }
  // sP reduce: combine threads with equal (tid&31); offsets all multiples of 32
  red[tid] = sP; __syncthreads();
  for (int off=512; off>=32; off>>=1){
    if (tid<off) red[tid] += red[tid+off];
    __syncthreads();
  }
  if (tid<32) bp[(size_t)o*K1 + tid] = __float2bfloat16(red[tid]);
  __syncthreads();
  // tP reduce: full tree
  red[tid] = tP; __syncthreads();
  for (int off=512; off; off>>=1){
    if (tid<off) red[tid] += red[tid+off];
    __syncthreads();
  }
  if (tid==0) ws[WS_K+o] = red[0] + bc1[o];
  // tails: 1024-elem packB copy, 512-elem Wc2 row
  bp[(size_t)o*K1 + 32 + tid] = __float2bfloat16(wr[16384+tid]);
  if (tid < 512) w2b[o*512+tid] = __float2bfloat16(Wc2[o*512+tid]);
}

// ============ bf16 MFMA GEMM: C = A(MxK)·B(NxK)^T, 64x64 tile ==============
template<bool RELU, bool BF16OUT>
__global__ __launch_bounds__(256)
void gemm_mfma(const bf16* __restrict__ A, const bf16* __restrict__ B,
               const float* __restrict__ bias, float* __restrict__ Cf,
               bf16* __restrict__ Cb, int M, int N, int K){
  __shared__ short Als[2048];
  __shared__ short Bls[2048];
  const int tid = threadIdx.x;
  const int bm = blockIdx.y*64, bn = blockIdx.x*64;
  const int wave = tid>>6, lane = tid&63;
  const int wm = wave>>1, wn = wave&1;
  const int r = lane&15, q = lane>>4;
  f32x4 acc[2][2] = {};
  const int lrow = tid>>2, lq = tid&3;
  const bf16* Ag = A + (size_t)(bm+lrow)*K + lq*8;
  const bf16* Bg = B + (size_t)(bn+lrow)*K + lq*8;
  const int sidx = (lq*64+lrow)*8;
  for (int k0=0; k0<K; k0+=32){
    float4 av = *(const float4*)(Ag + k0);
    float4 bv = *(const float4*)(Bg + k0);
    *(float4*)(&Als[sidx]) = av;
    *(float4*)(&Bls[sidx]) = bv;
    __syncthreads();
    #pragma unroll
    for (int i=0;i<2;i++){
      bf16x8 af = *(const bf16x8*)(&Als[(q*64 + wm*32 + i*16 + r)*8]);
      #pragma unroll
      for (int j=0;j<2;j++){
        bf16x8 bfr = *(const bf16x8*)(&Bls[(q*64 + wn*32 + j*16 + r)*8]);
        acc[i][j] = __builtin_amdgcn_mfma_f32_16x16x32_bf16(af, bfr, acc[i][j], 0,0,0);
      }
    }
    __syncthreads();
  }
  #pragma unroll
  for (int i=0;i<2;i++){
    int row = bm + wm*32 + i*16 + q*4;
    #pragma unroll
    for (int j=0;j<2;j++){
      int col = bn + wn*32 + j*16 + r;
      float bi = bias ? bias[col] : 0.f;
      #pragma unroll
      for (int g=0; g<4; g++){
        float v = acc[i][j][g] + bi;
        if (RELU) v = fmaxf(v, 0.f);
        if (BF16OUT) Cb[(size_t)(row+g)*N + col] = __float2bfloat16(v);
        else         Cf[(size_t)(row+g)*N + col] = v;
      }
    }
  }
}

extern "C" void kernel_launch(void* const* d_in, const int* in_sizes, int n_in,
                              void* d_out, int out_size, void* d_ws, size_t ws_size,
                              hipStream_t stream){
  const float* dist   = (const float*)d_in[0];
  const float* markov = (const float*)d_in[1];
  const float* demand = (const float*)d_in[2];
  const float* Wweek  = (const float*)d_in[3];
  const float* Wcap   = (const float*)d_in[4];
  const float* Wveh   = (const float*)d_in[5];
  const float* g1W    = (const float*)d_in[6];
  const float* g1as   = (const float*)d_in[7];
  const float* g1ad   = (const float*)d_in[8];
  const float* g1We   = (const float*)d_in[9];
  const float* g1ae   = (const float*)d_in[10];
  const float* g1b    = (const float*)d_in[11];
  const float* g2W    = (const float*)d_in[12];
  const float* g2as   = (const float*)d_in[13];
  const float* g2ad   = (const float*)d_in[14];
  const float* g2We   = (const float*)d_in[15];
  const float* g2ae   = (const float*)d_in[16];
  const float* g2b    = (const float*)d_in[17];
  const float* Wes    = (const float*)d_in[18];
  const float* bes    = (const float*)d_in[19];
  const float* Wc1    = (const float*)d_in[20];
  const float* bc1    = (const float*)d_in[21];
  const float* Wc2    = (const float*)d_in[22];
  const float* bc2    = (const float*)d_in[23];
  const int*   stops  = (const int*)d_in[24];
  const int*   eidx   = (const int*)d_in[25];
  const int*   wd     = (const int*)d_in[26];
  const int*   vh     = (const int*)d_in[27];
  const int*   cp     = (const int*)d_in[28];
  float* out = (float*)d_out;
  float* ws = (float*)d_ws;

  const int*   csrc   = (const int*)(ws+WS_CSRC);
  const float* cea    = ws+WS_CEA;
  const int*   starts = (const int*)(ws+WS_STARTS);
  const int*   deg    = (const int*)(ws+WS_DEG);
  const float* lattr  = ws+WS_LATTR;

  // K1: all input-only prep (+ histogram partials, cursor zero)
  k_prep<<<676,256,0,stream>>>(demand, g1W, g1as, g1ad, stops, Wes, dist, markov, eidx,
                               g1We, g1ae, g2We, g2ae, g2W, g2as, g2ad, ws);
  // K2: merged scan + scatter
  k_scansc<<<32,512,0,stream>>>(eidx, ws);
  // K3: GAT layer-1 aggregate + h2 + logits-2 epilogue
  k_agg<1><<<512,256,0,stream>>>(ws+WS_H, ws+WS_ASRC, ws+WS_ADST, csrc, cea, starts, deg,
                                 lattr, ws+WS_AE, g1b, dist, markov, ws);
  // K4: GAT layer-2 aggregate + uv + packA epilogue
  k_agg<2><<<512,256,0,stream>>>(ws+WS_H2, ws+WS_ASRC2, ws+WS_ADST2, csrc, cea, starts, deg,
                                 lattr, ws+WS_AE+8, g2b, dist, markov, ws);
  // K5: sk + packB + Wc2->bf16 (1024 threads, ILP-unrolled)
  k_skpack<<<512,1024,0,stream>>>(Wc1, bc1, bes, Wweek, Wcap, Wveh, wd, vh, cp, Wc2, ws);
  // K6/K7: decoder MFMA GEMMs
  gemm_mfma<true,true><<<dim3(8,8),256,0,stream>>>((const bf16*)(ws+WS_APACK), (const bf16*)(ws+WS_BPACK),
                                                   ws+WS_K, nullptr, (bf16*)(ws+WS_OUT1), 512, 512, K1);
  gemm_mfma<false,false><<<dim3(8,8),256,0,stream>>>((const bf16*)(ws+WS_OUT1), (const bf16*)(ws+WS_WC2B),
                                                     bc2, out, nullptr, 512, 512, 512);
}